// Round 11
// baseline (159.838 us; speedup 1.0000x reference)
//
#include <hip/hip_runtime.h>
#include <stdint.h>

#define B_ 2
#define T_ 2048
#define C_ 1024
#define H_ 16
#define D_ 64
#define M_ (B_*T_)   // 4096

typedef __attribute__((ext_vector_type(8))) short bf16x8;   // 8 bf16 in 4 VGPRs
typedef __attribute__((ext_vector_type(4))) short bf16x4;   // 4 bf16 in 2 VGPRs
typedef __attribute__((ext_vector_type(4))) __bf16 bf16v4;  // native bf16 quad (for HW cvt_pk)
typedef __attribute__((ext_vector_type(4))) float f32x4;
typedef unsigned short u16;

#define MFMA32(a, b, c) __builtin_amdgcn_mfma_f32_16x16x32_bf16((a), (b), (c), 0, 0, 0)

__device__ __forceinline__ u16 f2bf(float f) {
  union { float f; uint32_t u; } v; v.f = f;
  uint32_t u = v.u;
  return (u16)((u + 0x7fffu + ((u >> 16) & 1u)) >> 16);   // RNE
}

// v_exp_f32 (2^x) without touching libm headers (__exp2f collides with glibc macros)
__device__ __forceinline__ float exp2_fast(float x) { return __builtin_amdgcn_exp2f(x); }

typedef const __attribute__((address_space(1))) void* gas_t;
typedef __attribute__((address_space(3))) void* las_t;
__device__ __forceinline__ void gld_lds16(const void* g, void* l) {
  __builtin_amdgcn_global_load_lds((gas_t)g, (las_t)l, 16, 0, 0);
}

// ---------------- fp32 -> bf16 convert: x + all 4 weights in ONE launch ----------------
__global__ void cvt_all(const float* __restrict__ x,
                        const float* __restrict__ w0, const float* __restrict__ w1,
                        const float* __restrict__ w2, const float* __restrict__ w3,
                        u16* __restrict__ xb,
                        u16* __restrict__ d0, u16* __restrict__ d1,
                        u16* __restrict__ d2, u16* __restrict__ d3) {
  size_t i = ((size_t)blockIdx.x * 256 + threadIdx.x) * 4;
  const float* s; u16* d; size_t off;
  const size_t NX = (size_t)M_ * C_;        // 4M
  const size_t NW = (size_t)C_ * C_;        // 1M
  if (i < NX) { s = x; d = xb; off = i; }
  else {
    size_t j = i - NX;
    int w = (int)(j / NW); off = j - (size_t)w * NW;
    switch (w) {
      case 0: s = w0; d = d0; break;
      case 1: s = w1; d = d1; break;
      case 2: s = w2; d = d2; break;
      default: s = w3; d = d3; break;
    }
  }
  float4 v = *(const float4*)(s + off);
  ushort4 o;
  o.x = f2bf(v.x); o.y = f2bf(v.y); o.z = f2bf(v.z); o.w = f2bf(v.w);
  *(ushort4*)(d + off) = o;
}

// ---------------- GEMM core: C[128x128] = A[M,K] * W[N,K]^T (bf16) ----------------
// v12 = v9 exact (session best, 155.2us). v10 (QK-fuse, mixed durations at
// 2/CU) and v11 (gemm_out launch_bounds 4) both regressed; reverted.
// SESSION RULES learned: (1) don't mix block durations unless grid >> CUs;
// (2) uniform small blocks at 3/CU beat a better MFMA:ds ratio at 2/CU;
// (3) don't tighten VGPR caps on kernels that already fit their occupancy.
__device__ __forceinline__ void gemm_core(const u16* __restrict__ A,
                                          const u16* __restrict__ W,
                                          int m0, int n0, int Kt,
                                          f32x4 acc[4][4])
{
  __shared__ u16 As[128*64];
  __shared__ u16 Bs[128*64];
  const int t = threadIdx.x;
  const int lane = t & 63;
  const int wave = t >> 6;
  const int q = lane >> 4;
  const int l15 = lane & 15;
  const int wm = (wave >> 1) * 64;
  const int wn = (wave & 1) * 64;

  #pragma unroll
  for (int i = 0; i < 4; ++i)
    #pragma unroll
    for (int j = 0; j < 4; ++j)
      acc[i][j] = (f32x4){0.f, 0.f, 0.f, 0.f};

  for (int k0 = 0; k0 < Kt; k0 += 64) {
    #pragma unroll
    for (int r = 0; r < 4; ++r) {
      int Lc = r * 256 + t;
      int row = Lc >> 3;
      int gcc = (Lc & 7) ^ (row & 7);
      gld_lds16(A + (size_t)(m0 + row) * Kt + k0 + gcc * 8, As + Lc * 8);
    }
    #pragma unroll
    for (int r = 0; r < 4; ++r) {
      int Lc = r * 256 + t;
      int row = Lc >> 3;
      int gcc = (Lc & 7) ^ (row & 7);
      gld_lds16(W + (size_t)(n0 + row) * Kt + k0 + gcc * 8, Bs + Lc * 8);
    }
    __syncthreads();

    #pragma unroll
    for (int kk = 0; kk < 2; ++kk) {
      bf16x8 af[4], bfr[4];
      #pragma unroll
      for (int i = 0; i < 4; ++i) {
        int m = wm + i * 16 + l15;
        int ch = (kk * 4 + q) ^ (m & 7);
        af[i] = *(const bf16x8*)(As + m * 64 + ch * 8);
      }
      #pragma unroll
      for (int j = 0; j < 4; ++j) {
        int n = wn + j * 16 + l15;
        int ch = (kk * 4 + q) ^ (n & 7);
        bfr[j] = *(const bf16x8*)(Bs + n * 64 + ch * 8);
      }
      #pragma unroll
      for (int i = 0; i < 4; ++i)
        #pragma unroll
        for (int j = 0; j < 4; ++j)
          acc[i][j] = MFMA32(af[i], bfr[j], acc[i][j]);
    }
    __syncthreads();
  }
}

// ---------------- fused QKV projection ----------------
// Q pre-scaled by (1/sqrt(D)) * log2(e) so attention can use exp2 directly.
// Q/K segments run TRANSPOSED (A = weight, B = X) -> coalesced ushort4 stores.
// V stored transposed [b,h][d][pos] with pos = key-permutation within each
// 32-token block: pos = (k&~31)|((k&12)<<1)|((k&16)>>2)|(k&3)  (see attn).
#define QSCALE 0.1803368801111244f
__global__ __launch_bounds__(256, 3)
void gemm_qkv(const u16* __restrict__ X,
              const u16* __restrict__ Wq, const u16* __restrict__ Wk,
              const u16* __restrict__ Wv,
              u16* __restrict__ Q, u16* __restrict__ K, u16* __restrict__ Vt)
{
  const int bm = blockIdx.x;          // token-block 0..31
  const int bn = blockIdx.y;          // 0..23
  const int seg = bn >> 3;            // 0=Q 1=K 2=V
  const int nb = (bn & 7) * 128;      // output-dim block

  const int t = threadIdx.x, lane = t & 63, wave = t >> 6;
  const int q = lane >> 4, l15 = lane & 15;
  const int wm = (wave >> 1) * 64, wn = (wave & 1) * 64;

  f32x4 acc[4][4];

  if (seg < 2) {
    // ---- transposed: C[o][tok] = W[o][k] * X[tok][k] ----
    const u16* W = (seg == 0) ? Wq : Wk;
    gemm_core(W, X, nb, bm * 128, C_, acc);
    u16* dst = (seg == 0) ? Q : K;
    const float scale = (seg == 0) ? QSCALE : 1.0f;
    #pragma unroll
    for (int i = 0; i < 4; ++i) {
      #pragma unroll
      for (int j = 0; j < 4; ++j) {
        const int o = nb + wm + i * 16 + q * 4;      // output-dim base (mod 4 == 0)
        const int h = o >> 6, d = o & 63;
        const int mtok = bm * 128 + wn + j * 16 + l15;
        const int b = mtok >> 11, tt = mtok & (T_ - 1);
        ushort4 pk;
        pk.x = f2bf(acc[i][j][0] * scale); pk.y = f2bf(acc[i][j][1] * scale);
        pk.z = f2bf(acc[i][j][2] * scale); pk.w = f2bf(acc[i][j][3] * scale);
        *(ushort4*)(dst + (((size_t)(b * H_ + h)) * T_ + tt) * D_ + d) = pk;
      }
    }
  } else {
    // ---- normal orientation: r-index runs along tokens -> pack along t ----
    gemm_core(X, Wv, bm * 128, nb, C_, acc);
    #pragma unroll
    for (int i = 0; i < 4; ++i) {
      #pragma unroll
      for (int j = 0; j < 4; ++j) {
        const int mbase = bm * 128 + wm + i * 16 + q * 4;
        const int b = mbase >> 11, tt = mbase & (T_ - 1);
        const int n = nb + wn + j * 16 + l15;
        const int h = n >> 6, d = n & 63;
        const int ttp = (tt & ~31) | ((tt & 12) << 1) | ((tt & 16) >> 2);
        size_t idx = (((size_t)(b * H_ + h)) * D_ + d) * T_ + ttp;
        ushort4 pk;
        pk.x = f2bf(acc[i][j][0]); pk.y = f2bf(acc[i][j][1]);
        pk.z = f2bf(acc[i][j][2]); pk.w = f2bf(acc[i][j][3]);
        *(ushort4*)(Vt + idx) = pk;
      }
    }
  }
}

// ---------------- flash attention (causal), 8 waves, KEY-SPLIT groups, 4 tiles ----------------
// v9 (kept, best): wg0 = even 64-key sub-chunks, wg1 = odd, each for ALL 4
// tiles of the balanced quad {pr,15-pr,16+pr,31-pr}. Per-wave fragment reads
// halved (16 ds_read_b128 per 128-key chunk), amortized over 4 tiles;
// partials combined once at the end through the then-free LDS.
__global__ __launch_bounds__(512, 2)
void attn(const u16* __restrict__ Q, const u16* __restrict__ K,
          const u16* __restrict__ Vt, u16* __restrict__ Att)
{
  __shared__ u16 SM[32768 + 2048];
  const int t = threadIdx.x;
  const int lane = t & 63, wave = t >> 6;    // 0..7
  const int w4 = wave & 3, wg = wave >> 2;   // wg = sub-chunk parity
  const int q = lane >> 4, l15 = lane & 15;
  const int bh = blockIdx.x;                 // 0..31
  const int pr = blockIdx.y;                 // 0..7
  const int qb0 = pr * 64, qb1 = (15 - pr) * 64;
  const int qb2 = (16 + pr) * 64, qb3 = (31 - pr) * 64;   // qb3 = max
  int qb[4] = {qb0, qb1, qb2, qb3};
  const u16* Qp = Q + (size_t)bh * T_ * D_;
  const u16* Kp = K + (size_t)bh * T_ * D_;
  const u16* Vp = Vt + (size_t)bh * D_ * T_;

  int rowg[4];
  bf16x8 aq0[4], aq1[4];
  #pragma unroll
  for (int i = 0; i < 4; ++i) {
    rowg[i] = qb[i] + 4 * l15 + w4;
    const u16* qr = Qp + (size_t)rowg[i] * 64;
    aq0[i] = *(const bf16x8*)(qr + q * 8);
    aq1[i] = *(const bf16x8*)(qr + 32 + q * 8);
  }

  f32x4 o[4][4];
  float ls[4];
  #pragma unroll
  for (int i = 0; i < 4; ++i) {
    ls[i] = 0.f;
    #pragma unroll
    for (int j = 0; j < 4; ++j) o[i][j] = (f32x4){0.f, 0.f, 0.f, 0.f};
  }

  auto stage = [&](int kb, int buf) {
    u16* Ksb = SM + buf * 8192;
    u16* Vsb = SM + 16384 + buf * 8192;
    #pragma unroll
    for (int r = 0; r < 2; ++r) {
      int c = r * 512 + t, row = c >> 3, gcc = (c & 7) ^ (row & 7);
      gld_lds16(Kp + (size_t)(kb + row) * 64 + gcc * 8, Ksb + c * 8);
    }
    #pragma unroll
    for (int r = 0; r < 2; ++r) {
      int c = r * 512 + t, row = c >> 4, gcc = (c & 15) ^ (row & 15);
      gld_lds16(Vp + (size_t)row * T_ + kb + gcc * 8, Vsb + c * 8);
    }
  };

  stage(0, 0);
  int cur = 0;
  for (int kb = 0; kb <= qb3; kb += 128, cur ^= 1) {
    __syncthreads();                         // drains cur's loads; guards buf reuse
    if (kb + 128 <= qb3) stage(kb + 128, cur ^ 1);
    const u16* Kc = SM + cur * 8192;
    const u16* Vc = SM + 16384 + cur * 8192;

    const int kbase = kb + wg * 64;          // this group's sub-chunk
    if (kbase <= qb3) {                      // group-uniform
      bf16x8 kf0[4], kf1[4];
      #pragma unroll
      for (int j2 = 0; j2 < 4; ++j2) {
        const int rw = wg * 64 + j2 * 16 + l15;
        kf0[j2] = *(const bf16x8*)(Kc + rw * 64 + ((q)     ^ (rw & 7)) * 8);
        kf1[j2] = *(const bf16x8*)(Kc + rw * 64 + ((4 + q) ^ (rw & 7)) * 8);
      }
      bf16x8 vf[4][2];
      #pragma unroll
      for (int j = 0; j < 4; ++j) {
        const int rw = j * 16 + l15;
        #pragma unroll
        for (int kk = 0; kk < 2; ++kk) {
          const int cc = ((2 * wg + kk) * 4 + q) ^ (rw & 15);
          vf[j][kk] = *(const bf16x8*)(Vc + rw * 128 + cc * 8);
        }
      }

      #pragma unroll
      for (int i = 0; i < 4; ++i) {
        if (kbase > qb[i]) continue;         // group-uniform: tile done/not ours
        const bool diag = (kbase == qb[i]);
        bf16x4 pb[4];
        #pragma unroll
        for (int j2 = 0; j2 < 4; ++j2) {
          f32x4 z = (f32x4){0.f, 0.f, 0.f, 0.f};
          __builtin_amdgcn_s_setprio(1);
          z = MFMA32(kf0[j2], aq0[i], z);    // S^T = K . Q^T
          z = MFMA32(kf1[j2], aq1[i], z);
          __builtin_amdgcn_s_setprio(0);
          if (diag) {
            #pragma unroll
            for (int r = 0; r < 4; ++r) {
              const int key = kbase + j2 * 16 + q * 4 + r;
              if (key > rowg[i]) z[r] = -1e30f;
            }
          }
          float p0 = exp2_fast(z[0]), p1 = exp2_fast(z[1]);
          float p2 = exp2_fast(z[2]), p3 = exp2_fast(z[3]);
          ls[i] += (p0 + p1) + (p2 + p3);
          bf16v4 bv;                          // native cvt -> v_cvt_pk_bf16_f32
          bv[0] = (__bf16)p0; bv[1] = (__bf16)p1;
          bv[2] = (__bf16)p2; bv[3] = (__bf16)p3;
          pb[j2] = __builtin_bit_cast(bf16x4, bv);
        }
        __builtin_amdgcn_s_setprio(1);
        #pragma unroll
        for (int kk = 0; kk < 2; ++kk) {
          const bf16x8 pc = __builtin_shufflevector(pb[2 * kk], pb[2 * kk + 1],
                                                    0, 1, 2, 3, 4, 5, 6, 7);
          #pragma unroll
          for (int j = 0; j < 4; ++j)
            o[i][j] = MFMA32(vf[j][kk], pc, o[i][j]);   // O^T += V^T . P^T
        }
        __builtin_amdgcn_s_setprio(0);
      }
    }
  }

  // ---- cross-group combine: wg1 -> LDS, wg0 adds ----
  __syncthreads();                           // all compute done; LDS free
  float4* red  = (float4*)SM;                // 4096 float4 = 64KB (O partials)
  float4* lred = (float4*)(SM + 32768);      // 256 float4 = 4KB (ls partials)
  if (wg == 1) {
    #pragma unroll
    for (int i = 0; i < 4; ++i)
      #pragma unroll
      for (int j = 0; j < 4; ++j) {
        float4 v = {o[i][j][0], o[i][j][1], o[i][j][2], o[i][j][3]};
        red[((i * 4 + w4) * 64 + lane) * 4 + j] = v;
      }
    float4 lv = {ls[0], ls[1], ls[2], ls[3]};
    lred[w4 * 64 + lane] = lv;
  }
  __syncthreads();
  if (wg == 0) {
    const float4 lv = lred[w4 * 64 + lane];
    ls[0] += lv.x; ls[1] += lv.y; ls[2] += lv.z; ls[3] += lv.w;
    const int b = bh >> 4, h = bh & 15;
    #pragma unroll
    for (int i = 0; i < 4; ++i) {
      #pragma unroll
      for (int j = 0; j < 4; ++j) {
        const float4 v = red[((i * 4 + w4) * 64 + lane) * 4 + j];
        o[i][j][0] += v.x; o[i][j][1] += v.y;
        o[i][j][2] += v.z; o[i][j][3] += v.w;
      }
      float l = ls[i];
      l += __shfl_xor(l, 16, 64); l += __shfl_xor(l, 32, 64);
      const float inv = __builtin_amdgcn_rcpf(l);
      #pragma unroll
      for (int j = 0; j < 4; ++j) {
        ushort4 pk;
        pk.x = f2bf(o[i][j][0] * inv); pk.y = f2bf(o[i][j][1] * inv);
        pk.z = f2bf(o[i][j][2] * inv); pk.w = f2bf(o[i][j][3] * inv);
        *(ushort4*)(Att + ((size_t)b * T_ + rowg[i]) * C_ + h * 64 + j * 16 + q * 4) = pk;
      }
    }
  }
}

// ---------------- output projection (transposed): fp32 out, float4 stores ----------------
// C[o][tok] = Wo[o][k] * Att[tok][k]; r-index runs along o -> float4 along n.
// v12: back to (256,2) — the v9/155.2 configuration. (256,4) regressed 3.6us:
// the 128-VGPR cap costs more than the extra occupancy buys.
__global__ __launch_bounds__(256, 2)
void gemm_out(const u16* __restrict__ Att, const u16* __restrict__ Wo,
              float* __restrict__ Out)
{
  __shared__ u16 As[64 * 64];     // Wo rows (64 outputs)
  __shared__ u16 Bs[128 * 64];    // Att rows (128 tokens)
  const int t = threadIdx.x;
  const int lane = t & 63, wave = t >> 6;
  const int q = lane >> 4, l15 = lane & 15;
  const int wm = (wave >> 1) * 32, wn = (wave & 1) * 64;
  const int m0 = blockIdx.x * 64;           // output-dim
  const int n0 = blockIdx.y * 128;          // tokens

  f32x4 acc[2][4];
  #pragma unroll
  for (int i = 0; i < 2; ++i)
    #pragma unroll
    for (int j = 0; j < 4; ++j)
      acc[i][j] = (f32x4){0.f, 0.f, 0.f, 0.f};

  for (int k0 = 0; k0 < C_; k0 += 64) {
    #pragma unroll
    for (int r = 0; r < 2; ++r) {
      int Lc = r * 256 + t, row = Lc >> 3, gcc = (Lc & 7) ^ (row & 7);
      gld_lds16(Wo + (size_t)(m0 + row) * C_ + k0 + gcc * 8, As + Lc * 8);
    }
    #pragma unroll
    for (int r = 0; r < 4; ++r) {
      int Lc = r * 256 + t, row = Lc >> 3, gcc = (Lc & 7) ^ (row & 7);
      gld_lds16(Att + (size_t)(n0 + row) * C_ + k0 + gcc * 8, Bs + Lc * 8);
    }
    __syncthreads();

    #pragma unroll
    for (int kk = 0; kk < 2; ++kk) {
      bf16x8 af[2], bfr[4];
      #pragma unroll
      for (int i = 0; i < 2; ++i) {
        int m = wm + i * 16 + l15;
        int ch = (kk * 4 + q) ^ (m & 7);
        af[i] = *(const bf16x8*)(As + m * 64 + ch * 8);
      }
      #pragma unroll
      for (int j = 0; j < 4; ++j) {
        int n = wn + j * 16 + l15;
        int ch = (kk * 4 + q) ^ (n & 7);
        bfr[j] = *(const bf16x8*)(Bs + n * 64 + ch * 8);
      }
      #pragma unroll
      for (int i = 0; i < 2; ++i)
        #pragma unroll
        for (int j = 0; j < 4; ++j)
          acc[i][j] = MFMA32(af[i], bfr[j], acc[i][j]);
    }
    __syncthreads();
  }

  #pragma unroll
  for (int i = 0; i < 2; ++i) {
    #pragma unroll
    for (int j = 0; j < 4; ++j) {
      const int o = m0 + wm + i * 16 + q * 4;        // mod 4 == 0 -> 16B aligned
      const int tok = n0 + wn + j * 16 + l15;
      float4 st = {acc[i][j][0], acc[i][j][1], acc[i][j][2], acc[i][j][3]};
      *(float4*)(Out + (size_t)tok * C_ + o) = st;
    }
  }
}

// ---------------- launcher ----------------
extern "C" void kernel_launch(void* const* d_in, const int* in_sizes, int n_in,
                              void* d_out, int out_size, void* d_ws, size_t ws_size,
                              hipStream_t stream) {
  const float* x  = (const float*)d_in[0];
  const float* wq = (const float*)d_in[1];
  const float* wk = (const float*)d_in[2];
  const float* wv = (const float*)d_in[3];
  const float* wo = (const float*)d_in[4];
  float* out = (float*)d_out;

  u16* ws  = (u16*)d_ws;
  u16* xb  = ws;
  u16* wqb = xb  + (size_t)M_ * C_;
  u16* wkb = wqb + (size_t)C_ * C_;
  u16* wvb = wkb + (size_t)C_ * C_;
  u16* wob = wvb + (size_t)C_ * C_;
  u16* Qb  = wob + (size_t)C_ * C_;    // [B,H,T,D]
  u16* Kb  = Qb  + (size_t)M_ * C_;    // [B,H,T,D]
  u16* Vtb = Kb  + (size_t)M_ * C_;    // [B,H,D,T] key-permuted
  u16* Atb = Vtb + (size_t)M_ * C_;    // [B,T,C]

  // 4M (x) + 4*1M (weights) elems, /4 per thread, /256 per block = 8192 blocks
  cvt_all<<<dim3((M_ * C_ + 4 * C_ * C_) / 1024), 256, 0, stream>>>(
      x, wq, wk, wv, wo, xb, wqb, wkb, wvb, wob);

  gemm_qkv<<<dim3(M_ / 128, 24), 256, 0, stream>>>(xb, wqb, wkb, wvb, Qb, Kb, Vtb);
  attn<<<dim3(B_ * H_, 8), 512, 0, stream>>>(Qb, Kb, Vtb, Atb);
  gemm_out<<<dim3(C_ / 64, M_ / 128), 256, 0, stream>>>(Atb, wob, out);
}

// Round 12
// 153.880 us; speedup vs baseline: 1.0387x; 1.0387x over previous
//
#include <hip/hip_runtime.h>
#include <stdint.h>

#define B_ 2
#define T_ 2048
#define C_ 1024
#define H_ 16
#define D_ 64
#define M_ (B_*T_)   // 4096

typedef __attribute__((ext_vector_type(8))) short bf16x8;   // 8 bf16 in 4 VGPRs
typedef __attribute__((ext_vector_type(4))) short bf16x4;   // 4 bf16 in 2 VGPRs
typedef __attribute__((ext_vector_type(4))) __bf16 bf16v4;  // native bf16 quad (for HW cvt_pk)
typedef __attribute__((ext_vector_type(4))) float f32x4;
typedef unsigned short u16;

#define MFMA32(a, b, c) __builtin_amdgcn_mfma_f32_16x16x32_bf16((a), (b), (c), 0, 0, 0)

__device__ __forceinline__ u16 f2bf(float f) {
  union { float f; uint32_t u; } v; v.f = f;
  uint32_t u = v.u;
  return (u16)((u + 0x7fffu + ((u >> 16) & 1u)) >> 16);   // RNE
}

// v_exp_f32 (2^x) without touching libm headers (__exp2f collides with glibc macros)
__device__ __forceinline__ float exp2_fast(float x) { return __builtin_amdgcn_exp2f(x); }

typedef const __attribute__((address_space(1))) void* gas_t;
typedef __attribute__((address_space(3))) void* las_t;
__device__ __forceinline__ void gld_lds16(const void* g, void* l) {
  __builtin_amdgcn_global_load_lds((gas_t)g, (las_t)l, 16, 0, 0);
}

// ---------------- fp32 -> bf16 convert: x + all 4 weights in ONE launch ----------------
__global__ void cvt_all(const float* __restrict__ x,
                        const float* __restrict__ w0, const float* __restrict__ w1,
                        const float* __restrict__ w2, const float* __restrict__ w3,
                        u16* __restrict__ xb,
                        u16* __restrict__ d0, u16* __restrict__ d1,
                        u16* __restrict__ d2, u16* __restrict__ d3) {
  size_t i = ((size_t)blockIdx.x * 256 + threadIdx.x) * 4;
  const float* s; u16* d; size_t off;
  const size_t NX = (size_t)M_ * C_;        // 4M
  const size_t NW = (size_t)C_ * C_;        // 1M
  if (i < NX) { s = x; d = xb; off = i; }
  else {
    size_t j = i - NX;
    int w = (int)(j / NW); off = j - (size_t)w * NW;
    switch (w) {
      case 0: s = w0; d = d0; break;
      case 1: s = w1; d = d1; break;
      case 2: s = w2; d = d2; break;
      default: s = w3; d = d3; break;
    }
  }
  float4 v = *(const float4*)(s + off);
  ushort4 o;
  o.x = f2bf(v.x); o.y = f2bf(v.y); o.z = f2bf(v.z); o.w = f2bf(v.w);
  *(ushort4*)(d + off) = o;
}

// ---------------- GEMM core: C[128x128] = A[M,K] * W[N,K]^T (bf16) ----------------
// v9-exact (session best). SESSION RULES: (1) don't mix block durations unless
// grid >> CUs; (2) uniform small blocks at 3/CU beat a better MFMA:ds ratio at
// 2/CU; (3) don't tighten VGPR caps on kernels that already fit; (4) run-to-run
// noise is +-3% — only >=4us mechanisms are readable.
__device__ __forceinline__ void gemm_core(const u16* __restrict__ A,
                                          const u16* __restrict__ W,
                                          int m0, int n0, int Kt,
                                          f32x4 acc[4][4])
{
  __shared__ u16 As[128*64];
  __shared__ u16 Bs[128*64];
  const int t = threadIdx.x;
  const int lane = t & 63;
  const int wave = t >> 6;
  const int q = lane >> 4;
  const int l15 = lane & 15;
  const int wm = (wave >> 1) * 64;
  const int wn = (wave & 1) * 64;

  #pragma unroll
  for (int i = 0; i < 4; ++i)
    #pragma unroll
    for (int j = 0; j < 4; ++j)
      acc[i][j] = (f32x4){0.f, 0.f, 0.f, 0.f};

  for (int k0 = 0; k0 < Kt; k0 += 64) {
    #pragma unroll
    for (int r = 0; r < 4; ++r) {
      int Lc = r * 256 + t;
      int row = Lc >> 3;
      int gcc = (Lc & 7) ^ (row & 7);
      gld_lds16(A + (size_t)(m0 + row) * Kt + k0 + gcc * 8, As + Lc * 8);
    }
    #pragma unroll
    for (int r = 0; r < 4; ++r) {
      int Lc = r * 256 + t;
      int row = Lc >> 3;
      int gcc = (Lc & 7) ^ (row & 7);
      gld_lds16(W + (size_t)(n0 + row) * Kt + k0 + gcc * 8, Bs + Lc * 8);
    }
    __syncthreads();

    #pragma unroll
    for (int kk = 0; kk < 2; ++kk) {
      bf16x8 af[4], bfr[4];
      #pragma unroll
      for (int i = 0; i < 4; ++i) {
        int m = wm + i * 16 + l15;
        int ch = (kk * 4 + q) ^ (m & 7);
        af[i] = *(const bf16x8*)(As + m * 64 + ch * 8);
      }
      #pragma unroll
      for (int j = 0; j < 4; ++j) {
        int n = wn + j * 16 + l15;
        int ch = (kk * 4 + q) ^ (n & 7);
        bfr[j] = *(const bf16x8*)(Bs + n * 64 + ch * 8);
      }
      #pragma unroll
      for (int i = 0; i < 4; ++i)
        #pragma unroll
        for (int j = 0; j < 4; ++j)
          acc[i][j] = MFMA32(af[i], bfr[j], acc[i][j]);
    }
    __syncthreads();
  }
}

// ---------------- fused QKV projection ----------------
// Q pre-scaled by (1/sqrt(D)) * log2(e) so attention can use exp2 directly.
// Q/K segments run TRANSPOSED (A = weight, B = X) -> coalesced ushort4 stores.
// V stored transposed [b,h][d][pos] with pos = key-permutation within each
// 32-token block: pos = (k&~31)|((k&12)<<1)|((k&16)>>2)|(k&3)  (see attn).
#define QSCALE 0.1803368801111244f
__global__ __launch_bounds__(256, 3)
void gemm_qkv(const u16* __restrict__ X,
              const u16* __restrict__ Wq, const u16* __restrict__ Wk,
              const u16* __restrict__ Wv,
              u16* __restrict__ Q, u16* __restrict__ K, u16* __restrict__ Vt)
{
  const int bm = blockIdx.x;          // token-block 0..31
  const int bn = blockIdx.y;          // 0..23
  const int seg = bn >> 3;            // 0=Q 1=K 2=V
  const int nb = (bn & 7) * 128;      // output-dim block

  const int t = threadIdx.x, lane = t & 63, wave = t >> 6;
  const int q = lane >> 4, l15 = lane & 15;
  const int wm = (wave >> 1) * 64, wn = (wave & 1) * 64;

  f32x4 acc[4][4];

  if (seg < 2) {
    // ---- transposed: C[o][tok] = W[o][k] * X[tok][k] ----
    const u16* W = (seg == 0) ? Wq : Wk;
    gemm_core(W, X, nb, bm * 128, C_, acc);
    u16* dst = (seg == 0) ? Q : K;
    const float scale = (seg == 0) ? QSCALE : 1.0f;
    #pragma unroll
    for (int i = 0; i < 4; ++i) {
      #pragma unroll
      for (int j = 0; j < 4; ++j) {
        const int o = nb + wm + i * 16 + q * 4;      // output-dim base (mod 4 == 0)
        const int h = o >> 6, d = o & 63;
        const int mtok = bm * 128 + wn + j * 16 + l15;
        const int b = mtok >> 11, tt = mtok & (T_ - 1);
        ushort4 pk;
        pk.x = f2bf(acc[i][j][0] * scale); pk.y = f2bf(acc[i][j][1] * scale);
        pk.z = f2bf(acc[i][j][2] * scale); pk.w = f2bf(acc[i][j][3] * scale);
        *(ushort4*)(dst + (((size_t)(b * H_ + h)) * T_ + tt) * D_ + d) = pk;
      }
    }
  } else {
    // ---- normal orientation: r-index runs along tokens -> pack along t ----
    gemm_core(X, Wv, bm * 128, nb, C_, acc);
    #pragma unroll
    for (int i = 0; i < 4; ++i) {
      #pragma unroll
      for (int j = 0; j < 4; ++j) {
        const int mbase = bm * 128 + wm + i * 16 + q * 4;
        const int b = mbase >> 11, tt = mbase & (T_ - 1);
        const int n = nb + wn + j * 16 + l15;
        const int h = n >> 6, d = n & 63;
        const int ttp = (tt & ~31) | ((tt & 12) << 1) | ((tt & 16) >> 2);
        size_t idx = (((size_t)(b * H_ + h)) * D_ + d) * T_ + ttp;
        ushort4 pk;
        pk.x = f2bf(acc[i][j][0]); pk.y = f2bf(acc[i][j][1]);
        pk.z = f2bf(acc[i][j][2]); pk.w = f2bf(acc[i][j][3]);
        *(ushort4*)(Vt + idx) = pk;
      }
    }
  }
}

// ---------------- flash attention (causal), 8 waves, KEY-SPLIT groups, 4 tiles ----------------
// v9 (kept, best): wg0 = even 64-key sub-chunks, wg1 = odd, each for ALL 4
// tiles of the balanced quad {pr,15-pr,16+pr,31-pr}. Per-wave fragment reads
// halved (16 ds_read_b128 per 128-key chunk), amortized over 4 tiles;
// partials combined once at the end through the then-free LDS.
__global__ __launch_bounds__(512, 2)
void attn(const u16* __restrict__ Q, const u16* __restrict__ K,
          const u16* __restrict__ Vt, u16* __restrict__ Att)
{
  __shared__ u16 SM[32768 + 2048];
  const int t = threadIdx.x;
  const int lane = t & 63, wave = t >> 6;    // 0..7
  const int w4 = wave & 3, wg = wave >> 2;   // wg = sub-chunk parity
  const int q = lane >> 4, l15 = lane & 15;
  const int bh = blockIdx.x;                 // 0..31
  const int pr = blockIdx.y;                 // 0..7
  const int qb0 = pr * 64, qb1 = (15 - pr) * 64;
  const int qb2 = (16 + pr) * 64, qb3 = (31 - pr) * 64;   // qb3 = max
  int qb[4] = {qb0, qb1, qb2, qb3};
  const u16* Qp = Q + (size_t)bh * T_ * D_;
  const u16* Kp = K + (size_t)bh * T_ * D_;
  const u16* Vp = Vt + (size_t)bh * D_ * T_;

  int rowg[4];
  bf16x8 aq0[4], aq1[4];
  #pragma unroll
  for (int i = 0; i < 4; ++i) {
    rowg[i] = qb[i] + 4 * l15 + w4;
    const u16* qr = Qp + (size_t)rowg[i] * 64;
    aq0[i] = *(const bf16x8*)(qr + q * 8);
    aq1[i] = *(const bf16x8*)(qr + 32 + q * 8);
  }

  f32x4 o[4][4];
  float ls[4];
  #pragma unroll
  for (int i = 0; i < 4; ++i) {
    ls[i] = 0.f;
    #pragma unroll
    for (int j = 0; j < 4; ++j) o[i][j] = (f32x4){0.f, 0.f, 0.f, 0.f};
  }

  auto stage = [&](int kb, int buf) {
    u16* Ksb = SM + buf * 8192;
    u16* Vsb = SM + 16384 + buf * 8192;
    #pragma unroll
    for (int r = 0; r < 2; ++r) {
      int c = r * 512 + t, row = c >> 3, gcc = (c & 7) ^ (row & 7);
      gld_lds16(Kp + (size_t)(kb + row) * 64 + gcc * 8, Ksb + c * 8);
    }
    #pragma unroll
    for (int r = 0; r < 2; ++r) {
      int c = r * 512 + t, row = c >> 4, gcc = (c & 15) ^ (row & 15);
      gld_lds16(Vp + (size_t)row * T_ + kb + gcc * 8, Vsb + c * 8);
    }
  };

  stage(0, 0);
  int cur = 0;
  for (int kb = 0; kb <= qb3; kb += 128, cur ^= 1) {
    __syncthreads();                         // drains cur's loads; guards buf reuse
    if (kb + 128 <= qb3) stage(kb + 128, cur ^ 1);
    const u16* Kc = SM + cur * 8192;
    const u16* Vc = SM + 16384 + cur * 8192;

    const int kbase = kb + wg * 64;          // this group's sub-chunk
    if (kbase <= qb3) {                      // group-uniform
      bf16x8 kf0[4], kf1[4];
      #pragma unroll
      for (int j2 = 0; j2 < 4; ++j2) {
        const int rw = wg * 64 + j2 * 16 + l15;
        kf0[j2] = *(const bf16x8*)(Kc + rw * 64 + ((q)     ^ (rw & 7)) * 8);
        kf1[j2] = *(const bf16x8*)(Kc + rw * 64 + ((4 + q) ^ (rw & 7)) * 8);
      }
      bf16x8 vf[4][2];
      #pragma unroll
      for (int j = 0; j < 4; ++j) {
        const int rw = j * 16 + l15;
        #pragma unroll
        for (int kk = 0; kk < 2; ++kk) {
          const int cc = ((2 * wg + kk) * 4 + q) ^ (rw & 15);
          vf[j][kk] = *(const bf16x8*)(Vc + rw * 128 + cc * 8);
        }
      }

      #pragma unroll
      for (int i = 0; i < 4; ++i) {
        if (kbase > qb[i]) continue;         // group-uniform: tile done/not ours
        const bool diag = (kbase == qb[i]);
        bf16x4 pb[4];
        #pragma unroll
        for (int j2 = 0; j2 < 4; ++j2) {
          f32x4 z = (f32x4){0.f, 0.f, 0.f, 0.f};
          __builtin_amdgcn_s_setprio(1);
          z = MFMA32(kf0[j2], aq0[i], z);    // S^T = K . Q^T
          z = MFMA32(kf1[j2], aq1[i], z);
          __builtin_amdgcn_s_setprio(0);
          if (diag) {
            #pragma unroll
            for (int r = 0; r < 4; ++r) {
              const int key = kbase + j2 * 16 + q * 4 + r;
              if (key > rowg[i]) z[r] = -1e30f;
            }
          }
          float p0 = exp2_fast(z[0]), p1 = exp2_fast(z[1]);
          float p2 = exp2_fast(z[2]), p3 = exp2_fast(z[3]);
          ls[i] += (p0 + p1) + (p2 + p3);
          bf16v4 bv;                          // native cvt -> v_cvt_pk_bf16_f32
          bv[0] = (__bf16)p0; bv[1] = (__bf16)p1;
          bv[2] = (__bf16)p2; bv[3] = (__bf16)p3;
          pb[j2] = __builtin_bit_cast(bf16x4, bv);
        }
        __builtin_amdgcn_s_setprio(1);
        #pragma unroll
        for (int kk = 0; kk < 2; ++kk) {
          const bf16x8 pc = __builtin_shufflevector(pb[2 * kk], pb[2 * kk + 1],
                                                    0, 1, 2, 3, 4, 5, 6, 7);
          #pragma unroll
          for (int j = 0; j < 4; ++j)
            o[i][j] = MFMA32(vf[j][kk], pc, o[i][j]);   // O^T += V^T . P^T
        }
        __builtin_amdgcn_s_setprio(0);
      }
    }
  }

  // ---- cross-group combine: wg1 -> LDS, wg0 adds ----
  __syncthreads();                           // all compute done; LDS free
  float4* red  = (float4*)SM;                // 4096 float4 = 64KB (O partials)
  float4* lred = (float4*)(SM + 32768);      // 256 float4 = 4KB (ls partials)
  if (wg == 1) {
    #pragma unroll
    for (int i = 0; i < 4; ++i)
      #pragma unroll
      for (int j = 0; j < 4; ++j) {
        float4 v = {o[i][j][0], o[i][j][1], o[i][j][2], o[i][j][3]};
        red[((i * 4 + w4) * 64 + lane) * 4 + j] = v;
      }
    float4 lv = {ls[0], ls[1], ls[2], ls[3]};
    lred[w4 * 64 + lane] = lv;
  }
  __syncthreads();
  if (wg == 0) {
    const float4 lv = lred[w4 * 64 + lane];
    ls[0] += lv.x; ls[1] += lv.y; ls[2] += lv.z; ls[3] += lv.w;
    const int b = bh >> 4, h = bh & 15;
    #pragma unroll
    for (int i = 0; i < 4; ++i) {
      #pragma unroll
      for (int j = 0; j < 4; ++j) {
        const float4 v = red[((i * 4 + w4) * 64 + lane) * 4 + j];
        o[i][j][0] += v.x; o[i][j][1] += v.y;
        o[i][j][2] += v.z; o[i][j][3] += v.w;
      }
      float l = ls[i];
      l += __shfl_xor(l, 16, 64); l += __shfl_xor(l, 32, 64);
      const float inv = __builtin_amdgcn_rcpf(l);
      #pragma unroll
      for (int j = 0; j < 4; ++j) {
        ushort4 pk;
        pk.x = f2bf(o[i][j][0] * inv); pk.y = f2bf(o[i][j][1] * inv);
        pk.z = f2bf(o[i][j][2] * inv); pk.w = f2bf(o[i][j][3] * inv);
        *(ushort4*)(Att + ((size_t)b * T_ + rowg[i]) * C_ + h * 64 + j * 16 + q * 4) = pk;
      }
    }
  }
}

// ---------------- output projection (transposed): fp32 out, float4 stores ----------------
// C[o][tok] = Wo[o][k] * Att[tok][k]; r-index runs along o -> float4 along n.
// v13: BK 64 -> 128. Old structure paid 16 barrier-drains for 16 MFMA each
// (MFMA:ds = 1.33, ~430 TF vs qkv's 645 in the same skeleton). Now 8 K-steps
// with 32 MFMA per barrier-pair (ratio 2.67); staging bytes identical; LDS
// 24->48KB is free (occupancy grid-limited at 2 blocks/CU: 512 uniform
// blocks). 128-wide rows use the ^(row&15) 16-chunk XOR — same scheme as
// attn's V^T [64][128] buffer, measured 0 bank conflicts there. m132's BK=128
// regression was an occupancy loss (3->2 blocks/CU); not applicable here.
__global__ __launch_bounds__(256, 2)
void gemm_out(const u16* __restrict__ Att, const u16* __restrict__ Wo,
              float* __restrict__ Out)
{
  __shared__ u16 As[64 * 128];    // Wo rows (64 outputs)   16KB
  __shared__ u16 Bs[128 * 128];   // Att rows (128 tokens)  32KB
  const int t = threadIdx.x;
  const int lane = t & 63, wave = t >> 6;
  const int q = lane >> 4, l15 = lane & 15;
  const int wm = (wave >> 1) * 32, wn = (wave & 1) * 64;
  const int m0 = blockIdx.x * 64;           // output-dim
  const int n0 = blockIdx.y * 128;          // tokens

  f32x4 acc[2][4];
  #pragma unroll
  for (int i = 0; i < 2; ++i)
    #pragma unroll
    for (int j = 0; j < 4; ++j)
      acc[i][j] = (f32x4){0.f, 0.f, 0.f, 0.f};

  for (int k0 = 0; k0 < C_; k0 += 128) {
    // As: 64 rows x 16 chunks = 1024 chunks; linear LDS dest, source chunk
    // pre-swizzled gcc = cc ^ (row&15)  (both-sides rule: read undoes it)
    #pragma unroll
    for (int r = 0; r < 4; ++r) {
      int c = r * 256 + t, row = c >> 4, gcc = (c & 15) ^ (row & 15);
      gld_lds16(Wo + (size_t)(m0 + row) * C_ + k0 + gcc * 8, As + c * 8);
    }
    // Bs: 128 rows x 16 chunks = 2048 chunks
    #pragma unroll
    for (int r = 0; r < 8; ++r) {
      int c = r * 256 + t, row = c >> 4, gcc = (c & 15) ^ (row & 15);
      gld_lds16(Att + (size_t)(n0 + row) * C_ + k0 + gcc * 8, Bs + c * 8);
    }
    __syncthreads();

    #pragma unroll
    for (int s = 0; s < 2; ++s) {
      #pragma unroll
      for (int kk = 0; kk < 2; ++kk) {
        const int g = s * 8 + kk * 4 + q;    // global k-chunk within the 128
        bf16x8 af[2], bfr[4];
        #pragma unroll
        for (int i = 0; i < 2; ++i) {
          int m = wm + i * 16 + l15;
          int ch = g ^ (m & 15);
          af[i] = *(const bf16x8*)(As + m * 128 + ch * 8);
        }
        #pragma unroll
        for (int j = 0; j < 4; ++j) {
          int n = wn + j * 16 + l15;
          int ch = g ^ (n & 15);
          bfr[j] = *(const bf16x8*)(Bs + n * 128 + ch * 8);
        }
        #pragma unroll
        for (int i = 0; i < 2; ++i)
          #pragma unroll
          for (int j = 0; j < 4; ++j)
            acc[i][j] = MFMA32(af[i], bfr[j], acc[i][j]);
      }
    }
    __syncthreads();
  }

  #pragma unroll
  for (int i = 0; i < 2; ++i) {
    #pragma unroll
    for (int j = 0; j < 4; ++j) {
      const int o = m0 + wm + i * 16 + q * 4;        // mod 4 == 0 -> 16B aligned
      const int tok = n0 + wn + j * 16 + l15;
      float4 st = {acc[i][j][0], acc[i][j][1], acc[i][j][2], acc[i][j][3]};
      *(float4*)(Out + (size_t)tok * C_ + o) = st;
    }
  }
}

// ---------------- launcher ----------------
extern "C" void kernel_launch(void* const* d_in, const int* in_sizes, int n_in,
                              void* d_out, int out_size, void* d_ws, size_t ws_size,
                              hipStream_t stream) {
  const float* x  = (const float*)d_in[0];
  const float* wq = (const float*)d_in[1];
  const float* wk = (const float*)d_in[2];
  const float* wv = (const float*)d_in[3];
  const float* wo = (const float*)d_in[4];
  float* out = (float*)d_out;

  u16* ws  = (u16*)d_ws;
  u16* xb  = ws;
  u16* wqb = xb  + (size_t)M_ * C_;
  u16* wkb = wqb + (size_t)C_ * C_;
  u16* wvb = wkb + (size_t)C_ * C_;
  u16* wob = wvb + (size_t)C_ * C_;
  u16* Qb  = wob + (size_t)C_ * C_;    // [B,H,T,D]
  u16* Kb  = Qb  + (size_t)M_ * C_;    // [B,H,T,D]
  u16* Vtb = Kb  + (size_t)M_ * C_;    // [B,H,D,T] key-permuted
  u16* Atb = Vtb + (size_t)M_ * C_;    // [B,T,C]

  // 4M (x) + 4*1M (weights) elems, /4 per thread, /256 per block = 8192 blocks
  cvt_all<<<dim3((M_ * C_ + 4 * C_ * C_) / 1024), 256, 0, stream>>>(
      x, wq, wk, wv, wo, xb, wqb, wkb, wvb, wob);

  gemm_qkv<<<dim3(M_ / 128, 24), 256, 0, stream>>>(xb, wqb, wkb, wvb, Qb, Kb, Vtb);
  attn<<<dim3(B_ * H_, 8), 512, 0, stream>>>(Qb, Kb, Vtb, Atb);
  gemm_out<<<dim3(C_ / 64, M_ / 128), 256, 0, stream>>>(Atb, wob, out);
}